// Round 12
// baseline (160.770 us; speedup 1.0000x reference)
//
#include <hip/hip_runtime.h>

// Tile: 16 output rows x 64 output cols; 4 tiles per (n,c); grid 16384.
// R12: R11 base (70.7us) + S2 widened to 24-col chunks (126 thr = 42 rows x 3)
//      with STREAMED down-chain (output oi emitted when t2p[oi+5] ready ->
//      live window ~6 pairs, no VGPR blowup). Halo redundancy 2.83->2.42
//      t2/output: up-chain+act slots -15%, S2 LDS loads -25%.
//   S0 load -> S1 V-up(x2) -> S2 [H-up + act + H-down] fused -> S4 V-down + store.
//   s_in[26 x 80] : input rows gy0-5..gy0+20, cols -5..74 zero-padded   (bufA)
//   t1  [42 x 84] : vertical x2 up, cols 0..73 valid (ST1=84: S2 b128
//                   reads off the dr=2 bank collision of stride 80)     (bufB)
//   t3  [42 x 72] : H-up+act+H-down result, cols 0..63 valid            (bufA)
// LDS = (3024 + 3536 + 24)*4 = 26.3 KB -> 6 blocks/CU.
// h=2 garbage audit: w covers t1 cols 48..81; garbage cols >=74 (local s>=26)
// contaminate t2 m>=42 -> out cols >= 48+16 = 64 = pad (never read). Out col
// 63 (oi=15) reads w idx <=25 (t1 col 73, valid). Max t1 read 41*84+81=3525.
#define SIN 80
#define ST1 84
#define ST3 72

typedef float v2f __attribute__((ext_vector_type(2)));

static __device__ __forceinline__ v2f fma2(v2f a, v2f b, v2f c) {
    return __builtin_elementwise_fma(a, b, c);
}
static __device__ __forceinline__ v2f bcast2(float s) { v2f r; r.x = s; r.y = s; return r; }
static __device__ __forceinline__ v2f mk2(float a, float b) { v2f r; r.x = a; r.y = b; return r; }

__global__ __launch_bounds__(256, 4)
void synth_fused(const float* __restrict__ x, const float* __restrict__ bias,
                 const float* __restrict__ fu, const float* __restrict__ fd,
                 float* __restrict__ out)
{
    __shared__ __align__(16) float bufA[3024];   // s_in 26x80=2080 | t3 42x72=3024
    __shared__ __align__(16) float bufB[3536];   // t1 42x84=3528 + slack (reads to 3525)
    __shared__ float sfilt[24];
    float* const s_in = bufA;
    float* const s_t3 = bufA;
    float* const s_t1 = bufB;

    const int tid  = threadIdx.x;
    const int bx   = blockIdx.x;
    const int tile = bx & 3;
    const int nc   = bx >> 2;
    const int gy0  = tile << 4;

    if (tid < 24) sfilt[tid] = (tid < 12) ? fu[tid] : fd[tid - 12];
    const float bc = bias[nc & 511];
    const float* __restrict__ xc = x + ((size_t)nc << 12);

    // ---- S0: load 26 rows x 64 cols (float4 global, coalesced) + zero pad ----
    #pragma unroll
    for (int it = 0; it < 2; ++it) {
        int idx = tid + it * 256;
        if (idx < 416) {                         // 26 rows * 16 float4
            int r  = idx >> 4;
            int c4 = (idx & 15) << 2;
            int gy = gy0 - 5 + r;
            float4 v = make_float4(0.f, 0.f, 0.f, 0.f);
            if ((unsigned)gy < 64u)
                v = *reinterpret_cast<const float4*>(xc + (gy << 6) + c4);
            float* dst = s_in + r * SIN + 5 + c4;
            dst[0] = v.x; dst[1] = v.y; dst[2] = v.z; dst[3] = v.w;
        }
    }
    #pragma unroll
    for (int it = 0; it < 2; ++it) {                 // 26*16 pad slots (cols 0..4, 69..79)
        int idx = tid + it * 256;
        if (idx < 416) {
            int r  = idx >> 4;
            int pc = idx & 15;
            int c  = (pc < 5) ? pc : (64 + pc);
            s_in[r * SIN + c] = 0.0f;
        }
    }
    __syncthreads();

    // filter registers
    float u0[12], gs[12];
    #pragma unroll
    for (int k = 0; k < 12; ++k) { u0[k] = sfilt[k]; gs[k] = sfilt[23 - k]; }   // gs[k]=fd[11-k]
    v2f gpk[6];
    #pragma unroll
    for (int j = 0; j < 6; ++j) gpk[j] = mk2(gs[2*j], gs[2*j + 1]);

    // ---- S1: vertical x2 up, 2 cols/thread b64. 111 thr (g3 0..2, c2 0..36) ----
    // {t1[2m][2c2..+1], t1[2m+1][...]} = sum_j u0[10/11-2j] * s_in[7g3+m+j][2c2..+1]
    if (tid < 111) {
        const int g3 = tid / 37;
        const int c2 = tid - 37 * g3;
        const float* ip = s_in + (7 * g3) * SIN + 2 * c2;
        v2f rv[12];
        #pragma unroll
        for (int j = 0; j < 12; ++j) rv[j] = *reinterpret_cast<const v2f*>(ip + j * SIN);
        float* op = s_t1 + (14 * g3) * ST1 + 2 * c2;
        #pragma unroll
        for (int m = 0; m < 7; ++m) {
            v2f aE = rv[m] * u0[10];
            v2f aO = rv[m] * u0[11];
            #pragma unroll
            for (int j = 1; j < 6; ++j) {
                aE = fma2(rv[m + j], bcast2(u0[10 - 2*j]), aE);
                aO = fma2(rv[m + j], bcast2(u0[11 - 2*j]), aO);
            }
            *reinterpret_cast<v2f*>(op + (2*m) * ST1)     = aE;
            *reinterpret_cast<v2f*>(op + (2*m + 1) * ST1) = aO;
        }
    }
    __syncthreads();

    // fold x4 up-gain AND sqrt2 act-gain into H-up taps; sqrt2 into bias
    const float S42 = 4.0f * 1.41421356237309515f;
    v2f upk2[6];
    #pragma unroll
    for (int j = 0; j < 6; ++j) upk2[j] = mk2(u0[10 - 2*j] * S42, u0[11 - 2*j] * S42);
    const float bcs = bc * 1.41421356237309515f;

    // ---- S2: fused H-up + lrelu/clamp + H-down. 126 thr (r 0..41, h 0..2) ----
    // chunk h owns out cols 24h..24h+23; w = t1 cols 24h..24h+33 (17 pairs).
    // t2p[p] = act( sum_j upk2[j]*bcast(w[p+j]) + bc2 ), p 0..28 (op_sel bcast).
    // STREAMED down-chain: out oi = hadd(sum_j gpk[j]*t2p[oi+j]) emitted at
    // p = oi+5; 4-slot buffer -> b128 stores. Live t2p window ~6 pairs.
    if (tid < 126) {
        const int r = tid / 3;
        const int h = tid - 3 * r;
        const float* t1r = s_t1 + r * ST1 + 24 * h;
        v2f wp[17];
        #pragma unroll
        for (int j = 0; j < 8; ++j) {                  // 8 x b128 (16B-aligned: 84r+24h)
            float4 v4 = *reinterpret_cast<const float4*>(t1r + 4 * j);
            wp[2*j]     = mk2(v4.x, v4.y);
            wp[2*j + 1] = mk2(v4.z, v4.w);
        }
        wp[16] = *reinterpret_cast<const v2f*>(t1r + 32);
        const v2f bc2 = bcast2(bcs);
        v2f t2p[29];
        float* t3r = s_t3 + r * ST3 + 24 * h;
        float ob[4];
        #pragma unroll
        for (int p = 0; p < 29; ++p) {
            v2f acc = bc2;
            #pragma unroll
            for (int j = 0; j < 6; ++j) {
                const int s = p + j;
                const v2f wb = (s & 1)
                    ? __builtin_shufflevector(wp[s >> 1], wp[s >> 1], 1, 1)
                    : __builtin_shufflevector(wp[s >> 1], wp[s >> 1], 0, 0);
                acc = fma2(upk2[j], wb, acc);
            }
            v2f mx = __builtin_elementwise_max(acc, acc * 0.2f);
            t2p[p] = mk2(__builtin_amdgcn_fmed3f(mx.x, -256.0f, 256.0f),
                         __builtin_amdgcn_fmed3f(mx.y, -256.0f, 256.0f));
            if (p >= 5) {
                const int oi = p - 5;
                v2f a = gpk[0] * t2p[oi];
                #pragma unroll
                for (int j = 1; j < 6; ++j) a = fma2(gpk[j], t2p[oi + j], a);
                ob[oi & 3] = a.x + a.y;
                if ((oi & 3) == 3) {
                    float4 o4; o4.x = ob[0]; o4.y = ob[1]; o4.z = ob[2]; o4.w = ob[3];
                    *reinterpret_cast<float4*>(t3r + (oi - 3)) = o4;
                }
            }
        }
    }
    __syncthreads();

    // ---- S4: vertical /2 down, 1 col/thread b32 (conflict-free), 256 thr ----
    // out rows gy0+4rc..+3 at col c; reads t3 rows 8rc..8rc+17.
    {
        const int c  = tid & 63;
        const int rc = tid >> 6;
        const float* t3c = s_t3 + (rc << 3) * ST3 + c;
        float wv[18];
        #pragma unroll
        for (int j = 0; j < 18; ++j) wv[j] = t3c[j * ST3];
        float* op = out + ((size_t)nc << 12) + ((size_t)(gy0 + (rc << 2)) << 6) + c;
        #pragma unroll
        for (int i = 0; i < 4; ++i) {
            float acc = gs[0] * wv[2*i];
            #pragma unroll
            for (int k = 1; k < 12; ++k) acc = fmaf(gs[k], wv[2*i + k], acc);
            op[(size_t)(i << 6)] = acc;
        }
    }
}

extern "C" void kernel_launch(void* const* d_in, const int* in_sizes, int n_in,
                              void* d_out, int out_size, void* d_ws, size_t ws_size,
                              hipStream_t stream) {
    const float* x    = (const float*)d_in[0];
    const float* bias = (const float*)d_in[1];
    const float* fu   = (const float*)d_in[2];
    const float* fd   = (const float*)d_in[3];
    float* out        = (float*)d_out;

    dim3 grid(8 * 512 * 4);   // (n*c) x 4 row-tiles of 16x64
    dim3 block(256);
    hipLaunchKernelGGL(synth_fused, grid, block, 0, stream, x, bias, fu, fd, out);
}